// Round 4
// baseline (274.522 us; speedup 1.0000x reference)
//
#include <hip/hip_runtime.h>

// TPLoss: pred [B,N] fp32, labels [B,N] int32 (0/1) -> scalar fp32
//   s = sigmoid(pred); TP = sum(s*l); SP = sum(s); SL = sum(l)
//   denom = 1 - N + SP + SL - 2*TP ;  loss = -mean_b(TP/denom)
//
// R1-R3 lesson: 103.5us / 2.59 TB/s effective read BW across THREE different
// schedules (occupancy 30-67%, 2-16 loads in flight) -> hard read-path cap,
// not latency. R4 tests the last untested variable: two interleaved streams
// (bases differ by exactly 2^27 -> every pred/label pair collides in all
// address bits <21) vs phased single-stream access. Phase A: 16KB pred only,
// sigmoid in place; phase B: matching labels only, fma against held sigmoids.
// Empty asm pins defeat IR-level load sinking (which beat sched_barrier in R3).

typedef float f4v __attribute__((ext_vector_type(4)));
typedef int   i4v __attribute__((ext_vector_type(4)));

#define BDIM 256
#define WPB 4              // waves per block, one row each
#define ROWS 4096
#define COLS 8192
#define CHUNKS 32          // float4 chunks per lane per row (8192/64/4)
#define HALF 16            // chunks per phase pair (16KB pred / 16KB labels)

__global__ __launch_bounds__(BDIM) void tploss_rows(
    const float* __restrict__ pred,
    const int* __restrict__ labels,
    float* __restrict__ row_out)
{
    const int lane = threadIdx.x & 63;
    const int row  = blockIdx.x * WPB + (threadIdx.x >> 6);

    const f4v* pb = (const f4v*)(pred   + (size_t)row * COLS) + lane;
    const i4v* lb = (const i4v*)(labels + (size_t)row * COLS) + lane;

    float sp = 0.0f;   // sum sigmoid
    float tp = 0.0f;   // sum sigmoid*label
    int   sl = 0;      // sum label (exact)

    for (int h = 0; h < 2; ++h) {
        const f4v* ph = pb + h * HALF * 64;
        const i4v* lh = lb + h * HALF * 64;

        // ---- phase A: pred-only stream (16 KB per wave) ----
        f4v s[HALF];
#pragma unroll
        for (int i = 0; i < HALF; ++i) s[i] = ph[i * 64];
#pragma unroll
        for (int i = 0; i < HALF; ++i) asm volatile("" : "+v"(s[i]));  // pin: loads stay batched above

#pragma unroll
        for (int i = 0; i < HALF; ++i) {
            f4v v = s[i];
            f4v r;
            // sigmoid via v_exp + v_rcp (~2^-21 rel err; rcp(inf)=0 correct limit)
            r.x = __builtin_amdgcn_rcpf(1.0f + __expf(-v.x));
            r.y = __builtin_amdgcn_rcpf(1.0f + __expf(-v.y));
            r.z = __builtin_amdgcn_rcpf(1.0f + __expf(-v.z));
            r.w = __builtin_amdgcn_rcpf(1.0f + __expf(-v.w));
            sp += (r.x + r.y) + (r.z + r.w);
            s[i] = r;  // hold sigmoids for phase B
        }

        // ---- phase B: label-only stream, 2 batches of 8 ----
#pragma unroll
        for (int b = 0; b < 2; ++b) {
            i4v q[8];
#pragma unroll
            for (int i = 0; i < 8; ++i) q[i] = lh[(b * 8 + i) * 64];
#pragma unroll
            for (int i = 0; i < 8; ++i) asm volatile("" : "+v"(q[i]));

#pragma unroll
            for (int i = 0; i < 8; ++i) {
                f4v r = s[b * 8 + i];
                tp = fmaf(r.x, (float)q[i].x, tp);
                tp = fmaf(r.y, (float)q[i].y, tp);
                tp = fmaf(r.z, (float)q[i].z, tp);
                tp = fmaf(r.w, (float)q[i].w, tp);
                sl += (q[i].x + q[i].y) + (q[i].z + q[i].w);
            }
        }
    }

    float slf = (float)sl;

    // wave-64 butterfly; no LDS, no __syncthreads
#pragma unroll
    for (int off = 32; off > 0; off >>= 1) {
        sp  += __shfl_down(sp,  off, 64);
        tp  += __shfl_down(tp,  off, 64);
        slf += __shfl_down(slf, off, 64);
    }

    if (lane == 0) {
        float denom = 1.0f - (float)COLS + sp + slf - 2.0f * tp;
        row_out[row] = tp / denom;   // one plain store per row, no atomics
    }
}

__global__ __launch_bounds__(BDIM) void tploss_reduce(
    const float* __restrict__ row_out,
    float* __restrict__ out)
{
    const int tid = threadIdx.x;
    float s = 0.0f;
#pragma unroll
    for (int i = 0; i < ROWS / BDIM; ++i)
        s += row_out[i * BDIM + tid];

#pragma unroll
    for (int off = 32; off > 0; off >>= 1)
        s += __shfl_down(s, off, 64);

    __shared__ float sw[BDIM / 64];
    const int wave = tid >> 6;
    const int lane = tid & 63;
    if (lane == 0) sw[wave] = s;
    __syncthreads();

    if (tid == 0) {
        float tot = (sw[0] + sw[1]) + (sw[2] + sw[3]);
        out[0] = -tot * (1.0f / (float)ROWS);
    }
}

extern "C" void kernel_launch(void* const* d_in, const int* in_sizes, int n_in,
                              void* d_out, int out_size, void* d_ws, size_t ws_size,
                              hipStream_t stream) {
    const float* pred   = (const float*)d_in[0];
    const int*   labels = (const int*)d_in[1];
    float* row_out = (float*)d_ws;   // 4096 floats; fully overwritten each call

    tploss_rows<<<ROWS / WPB, BDIM, 0, stream>>>(pred, labels, row_out);
    tploss_reduce<<<1, BDIM, 0, stream>>>(row_out, (float*)d_out);
}

// Round 5
// 246.441 us; speedup vs baseline: 1.1139x; 1.1139x over previous
//
#include <hip/hip_runtime.h>

// TPLoss: pred [B,N] fp32, labels [B,N] int32 (0/1) -> scalar fp32
//   s = sigmoid(pred); TP = sum(s*l); SP = sum(s); SL = sum(l)
//   denom = 1 - N + SP + SL - 2*TP ;  loss = -mean_b(TP/denom)
//
// R1-R4: 101-103us across four schedules (occupancy 25-67%, 2-16 loads in
// flight, interleaved vs phased streams). Per-CU read rate pinned at
// ~4.3 B/cycle == ~30 outstanding 128B lines at ~900cy latency (Little's
// law) -> consistent with a per-CU L1/TCP outstanding-fill cap, NOT HBM.
// R5 single-variable test: nontemporal loads (global_load ... nt) bypass
// L1 allocation; streaming data is read once so L1 adds nothing. If the
// fill-queue theory is right, per-CU BW rises 2-4x.

typedef float f4v __attribute__((ext_vector_type(4)));
typedef int   i4v __attribute__((ext_vector_type(4)));

#define BDIM 256
#define WPB 4              // waves per block, one row each
#define ROWS 4096
#define COLS 8192
#define HALF 16            // float4 chunks per phase (16KB pred / 16KB labels)

__global__ __launch_bounds__(BDIM) void tploss_rows(
    const float* __restrict__ pred,
    const int* __restrict__ labels,
    float* __restrict__ row_out)
{
    const int lane = threadIdx.x & 63;
    const int row  = blockIdx.x * WPB + (threadIdx.x >> 6);

    const f4v* pb = (const f4v*)(pred   + (size_t)row * COLS) + lane;
    const i4v* lb = (const i4v*)(labels + (size_t)row * COLS) + lane;

    float sp = 0.0f;   // sum sigmoid
    float tp = 0.0f;   // sum sigmoid*label
    int   sl = 0;      // sum label (exact)

    for (int h = 0; h < 2; ++h) {
        const f4v* ph = pb + h * HALF * 64;
        const i4v* lh = lb + h * HALF * 64;

        // ---- phase A: pred-only stream, nontemporal (L1-bypass) ----
        f4v s[HALF];
#pragma unroll
        for (int i = 0; i < HALF; ++i) s[i] = __builtin_nontemporal_load(&ph[i * 64]);
#pragma unroll
        for (int i = 0; i < HALF; ++i) asm volatile("" : "+v"(s[i]));  // pin: keep loads batched

#pragma unroll
        for (int i = 0; i < HALF; ++i) {
            f4v v = s[i];
            f4v r;
            // sigmoid via v_exp + v_rcp (~2^-21 rel err; rcp(inf)=0 correct limit)
            r.x = __builtin_amdgcn_rcpf(1.0f + __expf(-v.x));
            r.y = __builtin_amdgcn_rcpf(1.0f + __expf(-v.y));
            r.z = __builtin_amdgcn_rcpf(1.0f + __expf(-v.z));
            r.w = __builtin_amdgcn_rcpf(1.0f + __expf(-v.w));
            sp += (r.x + r.y) + (r.z + r.w);
            s[i] = r;  // hold sigmoids for phase B
        }

        // ---- phase B: label-only stream, nontemporal, 2 batches of 8 ----
#pragma unroll
        for (int b = 0; b < 2; ++b) {
            i4v q[8];
#pragma unroll
            for (int i = 0; i < 8; ++i) q[i] = __builtin_nontemporal_load(&lh[(b * 8 + i) * 64]);
#pragma unroll
            for (int i = 0; i < 8; ++i) asm volatile("" : "+v"(q[i]));

#pragma unroll
            for (int i = 0; i < 8; ++i) {
                f4v r = s[b * 8 + i];
                tp = fmaf(r.x, (float)q[i].x, tp);
                tp = fmaf(r.y, (float)q[i].y, tp);
                tp = fmaf(r.z, (float)q[i].z, tp);
                tp = fmaf(r.w, (float)q[i].w, tp);
                sl += (q[i].x + q[i].y) + (q[i].z + q[i].w);
            }
        }
    }

    float slf = (float)sl;

    // wave-64 butterfly; no LDS, no __syncthreads
#pragma unroll
    for (int off = 32; off > 0; off >>= 1) {
        sp  += __shfl_down(sp,  off, 64);
        tp  += __shfl_down(tp,  off, 64);
        slf += __shfl_down(slf, off, 64);
    }

    if (lane == 0) {
        float denom = 1.0f - (float)COLS + sp + slf - 2.0f * tp;
        row_out[row] = tp / denom;   // one plain store per row, no atomics
    }
}

__global__ __launch_bounds__(BDIM) void tploss_reduce(
    const float* __restrict__ row_out,
    float* __restrict__ out)
{
    const int tid = threadIdx.x;
    float s = 0.0f;
#pragma unroll
    for (int i = 0; i < ROWS / BDIM; ++i)
        s += row_out[i * BDIM + tid];

#pragma unroll
    for (int off = 32; off > 0; off >>= 1)
        s += __shfl_down(s, off, 64);

    __shared__ float sw[BDIM / 64];
    const int wave = tid >> 6;
    const int lane = tid & 63;
    if (lane == 0) sw[wave] = s;
    __syncthreads();

    if (tid == 0) {
        float tot = (sw[0] + sw[1]) + (sw[2] + sw[3]);
        out[0] = -tot * (1.0f / (float)ROWS);
    }
}

extern "C" void kernel_launch(void* const* d_in, const int* in_sizes, int n_in,
                              void* d_out, int out_size, void* d_ws, size_t ws_size,
                              hipStream_t stream) {
    const float* pred   = (const float*)d_in[0];
    const int*   labels = (const int*)d_in[1];
    float* row_out = (float*)d_ws;   // 4096 floats; fully overwritten each call

    tploss_rows<<<ROWS / WPB, BDIM, 0, stream>>>(pred, labels, row_out);
    tploss_reduce<<<1, BDIM, 0, stream>>>(row_out, (float*)d_out);
}